// Round 11
// baseline (147.179 us; speedup 1.0000x reference)
//
#include <hip/hip_runtime.h>
#include <math.h>

#define H 4096
#define W 4096
#define NC 512            // cells per dim (H/8)
#define NB 510            // blocks per dim (NC - 3 + 1)
#define ORI 9
#define NCELLS (NC * NC)  // 262144
#define NOUT (NB * NB * 81)  // 21068100

// ---- glibc flt-32 atanf/atan2f replication (fdlibm; pre-2.40 glibc) ----
__device__ __constant__ float c_atanhi[4] = {
    4.6364760399e-01f, 7.8539812565e-01f, 9.8279368877e-01f, 1.5707962513e+00f,
};
__device__ __constant__ float c_atanlo[4] = {
    5.0121582440e-09f, 3.7748947079e-08f, 3.4473217170e-08f, 7.5497894159e-08f,
};

__device__ float fdlibm_atanf(float x) {
#pragma clang fp contract(off)
    const float one = 1.0f;
    const float aT0  = (float) 3.33333333333329318027e-01;
    const float aT1  = (float)-1.99999999998764832476e-01;
    const float aT2  = (float) 1.42857142725034663711e-01;
    const float aT3  = (float)-1.11111104054623557880e-01;
    const float aT4  = (float) 9.09088713343650656196e-02;
    const float aT5  = (float)-7.69187620504482999495e-02;
    const float aT6  = (float) 6.66107313738753120669e-02;
    const float aT7  = (float)-5.83357013379057348645e-02;
    const float aT8  = (float) 4.97687799461593236017e-02;
    const float aT9  = (float)-3.65315727442169155270e-02;
    const float aT10 = (float) 1.62858201153657823623e-02;
    int hx = __float_as_int(x);
    int ix = hx & 0x7fffffff;
    int id;
    if (ix >= 0x4c800000) {
        if (ix > 0x7f800000) return x + x;
        float r = c_atanhi[3] + c_atanlo[3];
        return (hx > 0) ? r : -r;
    }
    if (ix < 0x3ee00000) {
        if (ix < 0x31000000) return x;
        id = -1;
    } else {
        x = fabsf(x);
        if (ix < 0x3f980000) {
            if (ix < 0x3f300000) { id = 0; x = (2.0f * x - one) / (2.0f + x); }
            else                 { id = 1; x = (x - one) / (x + one); }
        } else {
            if (ix < 0x401c0000) { id = 2; x = (x - 1.5f) / (one + 1.5f * x); }
            else                 { id = 3; x = -1.0f / x; }
        }
    }
    float z = x * x;
    float w = z * z;
    float s1 = z * (aT0 + w * (aT2 + w * (aT4 + w * (aT6 + w * (aT8 + w * aT10)))));
    float s2 = w * (aT1 + w * (aT3 + w * (aT5 + w * (aT7 + w * aT9))));
    if (id < 0) return x - x * (s1 + s2);
    z = c_atanhi[id] - ((x * (s1 + s2) - c_atanlo[id]) - x);
    return (hx < 0) ? -z : z;
}

__device__ float fdlibm_atan2f(float y, float x) {
#pragma clang fp contract(off)
    const float tiny   = 1.0e-30f;
    const float pi     = 3.1415927410e+00f;
    const float pi_lo  = -8.7422776573e-08f;
    const float pi_o_2 = 1.5707963705e+00f;
    int hx = __float_as_int(x), ix = hx & 0x7fffffff;
    int hy = __float_as_int(y), iy = hy & 0x7fffffff;
    if (ix > 0x7f800000 || iy > 0x7f800000) return x + y;
    if (hx == 0x3f800000) return fdlibm_atanf(y);
    int m = ((hy >> 31) & 1) | ((hx >> 30) & 2);
    if (iy == 0) {
        switch (m) {
            case 0: case 1: return y;
            case 2: return pi + tiny;
            default: return -pi - tiny;
        }
    }
    if (ix == 0) return (hy < 0) ? -pi_o_2 - tiny : pi_o_2 + tiny;
    if (ix == 0x7f800000) {
        if (iy == 0x7f800000) {
            switch (m) {
                case 0: return pi_o_2 * 0.5f + tiny;
                case 1: return -(pi_o_2 * 0.5f) - tiny;
                case 2: return 1.5f * pi_o_2 + tiny;
                default: return -(1.5f * pi_o_2) - tiny;
            }
        } else {
            switch (m) {
                case 0: return 0.0f;
                case 1: return -0.0f;
                case 2: return pi + tiny;
                default: return -pi - tiny;
            }
        }
    }
    if (iy == 0x7f800000) return (hy < 0) ? -pi_o_2 - tiny : pi_o_2 + tiny;
    int k = (iy - ix) >> 23;
    float z;
    if (k > 26) { z = pi_o_2 + 0.5f * pi_lo; m &= 1; }
    else if (k < -26 && hx < 0) z = 0.0f;
    else z = fdlibm_atanf(fabsf(y / x));
    switch (m) {
        case 0: return z;
        case 1: return -z;
        case 2: return pi - (z - pi_lo);
        default: return (z - pi_lo) - pi;
    }
}

// Exact-replica binning (slow path). Returns 0..8, or 9 == excluded (m==180 quirk).
__device__ __noinline__ int slow_bin(float gy, float gx) {
#pragma clang fp contract(off)
    float ang = fdlibm_atan2f(gy, gx);
    const float RAD2DEG = (float)(180.0 / 3.14159265358979323846264338328);
    float deg = ang * RAD2DEG;
    float m = fmodf(deg, 180.0f);
    if (m < 0.0f) m += 180.0f;
    int bin = (int)(m / 20.0f);
    if (bin < 9 && m >= (float)((bin + 1) * 20)) bin++;
    else if (bin > 0 && m < (float)(bin * 20)) bin--;
    return bin;
}

// Kernel A: block = 64x32 px tile (8x4 cells). Staging via 3 WIDE float4
// loads per thread (chain depth 1 instead of r10's 9 serial scalar loads),
// sqrt -> aligned ds_write_b64 pairs. LDS layout: image col col0+c at dword
// c+2; left halo (col0-1) at dword 1; right halo (col0+64) at dword 66.
// Compute: 9x ds_read_b128 per thread, tangent-threshold binning.
__global__ __launch_bounds__(256, 4) void hog_hist(const float* __restrict__ x,
                                                   float* __restrict__ hist,
                                                   float* __restrict__ q) {
    __shared__ __align__(16) float S[34 * 68];
    __shared__ float lh[4 * 72];                // per-wave 8 cells x 9 bins
    int t = threadIdx.x;
    int tcol = blockIdx.x & 63;
    int trow = blockIdx.x >> 6;
    int col0 = tcol << 6;
    int row0 = trow << 5;

    lh[t] = 0.0f;
    if (t < 32) lh[256 + t] = 0.0f;

    // ---- staging: 3 independent float4 loads per thread ----
    int f4c = t & 15;                 // float4 col 0..15
    int rr  = t >> 4;                 // row 0..15
    const float4* x4 = (const float4*)x;          // 1024 float4 per image row
    int c4 = (col0 >> 2) + f4c;
    int ga = row0 - 1 + rr;           // pass 0: staged rows 0..15
    int gb = ga + 16;                 // pass 1: staged rows 16..31 (always in range)
    int gc = ga + 32;                 // pass 2: staged rows 32..33 (rr<2)
    float4 va = make_float4(0.f, 0.f, 0.f, 0.f);
    float4 vb, vc = make_float4(0.f, 0.f, 0.f, 0.f);
    if (ga >= 0) va = x4[ga * 1024 + c4];
    vb = x4[gb * 1024 + c4];
    bool do_c = (rr < 2);
    if (do_c && gc < H) vc = x4[gc * 1024 + c4];
    // halo columns (scalar, spread over waves 1 and 2)
    float vh = 0.0f;
    if (t >= 64 && t < 98) {          // left halo rows 0..33
        int grow = row0 - 1 + (t - 64);
        if ((unsigned)grow < (unsigned)H && col0 >= 1) vh = x[grow * W + col0 - 1];
    } else if (t >= 128 && t < 162) { // right halo rows 0..33
        int grow = row0 - 1 + (t - 128);
        if ((unsigned)grow < (unsigned)H && col0 + 64 < W) vh = x[grow * W + col0 + 64];
    }

    // ---- sqrt + aligned LDS writes (ds_write_b64 pairs) ----
    {
        float2* d0 = (float2*)&S[rr * 68 + 4 * f4c + 2];
        d0[0] = make_float2(sqrtf(va.x), sqrtf(va.y));    // IEEE-exact
        d0[1] = make_float2(sqrtf(va.z), sqrtf(va.w));
        float2* d1 = (float2*)&S[(rr + 16) * 68 + 4 * f4c + 2];
        d1[0] = make_float2(sqrtf(vb.x), sqrtf(vb.y));
        d1[1] = make_float2(sqrtf(vb.z), sqrtf(vb.w));
        if (do_c) {
            float2* d2 = (float2*)&S[(rr + 32) * 68 + 4 * f4c + 2];
            d2[0] = make_float2(sqrtf(vc.x), sqrtf(vc.y));
            d2[1] = make_float2(sqrtf(vc.z), sqrtf(vc.w));
        }
        if (t >= 64 && t < 98)        S[(t - 64) * 68 + 1]  = sqrtf(vh);
        else if (t >= 128 && t < 162) S[(t - 128) * 68 + 66] = sqrtf(vh);
    }
    __syncthreads();   // the only barrier

    int cell = t & 7;
    int row  = t >> 3;               // 0..31
    int w    = t >> 6;
    int grow = row0 + row;
    int gc0  = col0 + (cell << 3);
    bool row_ok = (grow >= 1) && (grow <= H - 2);

    const float4* Sv = (const float4*)S;
    int fa = row * 17 + 2 * cell;            // dwords row*68 + 8*cell
    float A[12], O[12], B[12];
    *(float4*)&A[0] = Sv[fa];     *(float4*)&A[4] = Sv[fa + 1];  *(float4*)&A[8] = Sv[fa + 2];
    *(float4*)&O[0] = Sv[fa + 17];*(float4*)&O[4] = Sv[fa + 18]; *(float4*)&O[8] = Sv[fa + 19];
    *(float4*)&B[0] = Sv[fa + 34];*(float4*)&B[4] = Sv[fa + 35]; *(float4*)&B[8] = Sv[fa + 36];

    const float T1 = (float) 0.36397023426620236135;  // tan20
    const float T2 = (float) 0.83909963117728001176;  // tan40
    const float T3 = (float) 1.73205080756887729353;  // tan60
    const float T4 = (float) 5.67128181961771110517;  // tan80
    float* lw = &lh[w * 72 + cell * 9];

#pragma unroll
    for (int i = 0; i < 8; ++i) {
        // image col col0+8*cell+i-2+j at array index j: pixel at j=i+2
        float gy = row_ok ? (B[i + 2] - A[i + 2]) : 0.0f;
        unsigned gcu = (unsigned)(gc0 + i);
        float gx = (gcu - 1u < (unsigned)(W - 2)) ? (O[i + 3] - O[i + 1]) : 0.0f;

        float a = fabsf(gy), b = fabsf(gx);
        float d1 = fmaf(b, -T1, a);
        float d2 = fmaf(b, -T2, a);
        float d3 = fmaf(b, -T3, a);
        float d4 = fmaf(b, -T4, a);
        int cnt = (d1 > 0.0f) + (d2 > 0.0f) + (d3 > 0.0f) + (d4 > 0.0f);
        bool opp = ((__float_as_int(gy) ^ __float_as_int(gx)) < 0);
        int bin = opp ? 8 - cnt : cnt;

        float cm = fminf(fminf(fabsf(d1), fabsf(d2)), fminf(fabsf(d3), fabsf(d4)));
        cm = fminf(cm, a);
        if (cm < 1e-5f * (a + b)) bin = slow_bin(gy, gx);

        float mag = __builtin_amdgcn_sqrtf(fmaf(gy, gy, gx * gx)); // value-level only
        if (bin < ORI) atomicAdd(&lw[bin], mag);
    }

    // epilogue: wave-private lh -> hist (+ per-cell q); incl. the 64..71 fix.
    int lane = t & 63;
    int gcr = (row0 >> 3) + w;                       // global cell row
    int cbase = gcr * (NC * ORI) + tcol * 8 * ORI;
    hist[cbase + lane] = lh[w * 72 + lane] * (1.0f / 64.0f);
    if (lane < 8) {
        hist[cbase + 64 + lane] = lh[w * 72 + 64 + lane] * (1.0f / 64.0f);
        float qq = 0.0f;
#pragma unroll
        for (int o = 0; o < 9; ++o) {
            float h = lh[w * 72 + lane * 9 + o] * (1.0f / 64.0f);
            qq = fmaf(h, h, qq);
        }
        q[gcr * NC + tcol * 8 + lane] = qq;
    }
}

// Kernel B: inv(i,j) = rsqrt(3x3 box-sum of q + EPS^2)
__global__ __launch_bounds__(256) void hog_inv(const float* __restrict__ q,
                                               float* __restrict__ inv) {
    int t = blockIdx.x * 256 + threadIdx.x;
    if (t >= NB * NB) return;
    int i = t / NB;
    int j = t - i * NB;
    float ssq = 0.0f;
#pragma unroll
    for (int bi = 0; bi < 3; ++bi)
#pragma unroll
        for (int bj = 0; bj < 3; ++bj)
            ssq += q[(i + bi) * NC + (j + bj)];
    inv[t] = 1.0f / sqrtf(ssq + 1e-10f);
}

// Kernel C: thread per output element, coalesced stores.
__global__ __launch_bounds__(256) void hog_norm(const float* __restrict__ hist,
                                                const float* __restrict__ inv,
                                                float* __restrict__ out, int n) {
    int k = blockIdx.x * 256 + threadIdx.x;
    if (k >= n) return;
    int pidx = k / 81;
    int e = k - pidx * 81;
    int i = pidx / NB;
    int j = pidx - i * NB;
    int bi = e / 27;
    int r = e - bi * 27;
    int bj = r / 9;
    int o = r - bj * 9;
    out[k] = hist[((i + bi) * NC + (j + bj)) * ORI + o] * inv[pidx];
}

extern "C" void kernel_launch(void* const* d_in, const int* in_sizes, int n_in,
                              void* d_out, int out_size, void* d_ws, size_t ws_size,
                              hipStream_t stream) {
    const float* x = (const float*)d_in[0];
    float* out = (float*)d_out;
    float* hist = (float*)d_ws;                     // 9.44 MB
    float* inv  = hist + NCELLS * ORI;              // 1.04 MB
    // q (1 MB) parked in d_out's tail: written by A, consumed by B, then
    // fully overwritten by C (proven since round 7).
    float* q = out + (NOUT - NCELLS);

    hog_hist<<<64 * 128, 256, 0, stream>>>(x, hist, q);
    hog_inv<<<(NB * NB + 255) / 256, 256, 0, stream>>>(q, inv);
    hog_norm<<<(out_size + 255) / 256, 256, 0, stream>>>(hist, inv, out, out_size);
}